// Round 4
// baseline (515.266 us; speedup 1.0000x reference)
//
#include <hip/hip_runtime.h>
#include <stdint.h>

#define NB 16
#define CC 64
#define HH 256
#define WW 256
#define WP 258   // padded width (cols 0 and 257 are pad)

// ---- pack weights: bit c of word (o,kh,kw) = (w[o][c][kh][kw] < 0) ----
__global__ __launch_bounds__(256) void pack_w_kernel(const float* __restrict__ w,
                                                     uint64_t* __restrict__ pW) {
    int widx = (blockIdx.x * 256 + threadIdx.x) >> 6;  // one packed word per wave
    int lane = threadIdx.x & 63;                       // lane = input channel
    if (widx >= CC * 9) return;
    int o = widx / 9;
    int t = widx % 9;
    float v = w[(size_t)o * (CC * 9) + (size_t)lane * 9 + t];
    unsigned long long m = __ballot(v < 0.0f);
    if (lane == 0) pW[widx] = m;
}

// ---- fused pack + binary conv + bias + relu + eval BN ----
// Block = (n, 8-row stripe), 512 threads. Phase 1: pack 10 padded rows of x
// (8 own + 1 halo each side, borders zeroed) into an LDS tile; lanes 0..63 of
// wave 0 also stage per-o constants (packed W, border corrections, epilogue
// floats) into LDS. Phase 2: wave w -> output row h0+w, lane l -> pixel quad;
// X window 3x6 u64 from LDS into VGPRs once, then the o-loop reads weights via
// uniform-address LDS broadcasts and emits 1KB-contiguous wave stores.
// Fusion overlaps the 335MB read stream with the 268MB write stream on the
// shared HBM bus instead of serializing them across two kernels.
__global__ __launch_bounds__(512, 4) void fused_kernel(const float* __restrict__ x,
                                                       const uint64_t* __restrict__ pW,
                                                       const float* __restrict__ bias,
                                                       const float* __restrict__ gamma,
                                                       const float* __restrict__ beta,
                                                       const float* __restrict__ rmean,
                                                       const float* __restrict__ rvar,
                                                       float* __restrict__ out) {
    __shared__ uint64_t tile[10][WP];  // 20.6 KB: padded rows h0..h0+9
    __shared__ uint64_t sq[CC][9];     // packed weights
    __shared__ int si[CC][8];          // top,bot,left,right,ct0,ct2,ct6,ct8
    __shared__ float sf[CC][3];        // bias, inv, addc

    int blk = blockIdx.x;   // 0..511
    int n = blk >> 5;
    int h0 = (blk & 31) << 3;
    int tid = threadIdx.x;

    // per-o constants (one wave's worth of lanes)
    if (tid < CC) {
        int o = tid;
        int ct[9];
#pragma unroll
        for (int t = 0; t < 9; ++t) {
            uint64_t q = pW[o * 9 + t];
            sq[o][t] = q;
            ct[t] = 64 - 2 * __popcll(q);  // pad-tap correction (pad word = 0)
        }
        si[o][0] = ct[0] + ct[1] + ct[2];  // top
        si[o][1] = ct[6] + ct[7] + ct[8];  // bot
        si[o][2] = ct[0] + ct[3] + ct[6];  // left
        si[o][3] = ct[2] + ct[5] + ct[8];  // right
        si[o][4] = ct[0]; si[o][5] = ct[2]; si[o][6] = ct[6]; si[o][7] = ct[8];
        float inv = gamma[o] / sqrtf(rvar[o] + 1e-5f);
        sf[o][0] = bias[o];
        sf[o][1] = inv;
        sf[o][2] = beta[o] - rmean[o] * inv;
    }

    // pack 10 padded rows x 64 pixel-quads into LDS
    const float4* xv = (const float4*)x;
    for (int i = tid; i < 640; i += 512) {
        int r = i >> 6;            // padded row index within tile
        int g = i & 63;            // pixel quad
        int xr = h0 + r - 1;       // source x row
        uint64_t b0 = 0, b1 = 0, b2 = 0, b3 = 0;
        if (xr >= 0 && xr < HH) {
            size_t base = (((size_t)n * CC) << 14) + ((size_t)xr << 6) + g;
#pragma unroll 16
            for (int c = 0; c < CC; ++c) {
                float4 v = xv[base + ((size_t)c << 14)];  // 1KB contiguous per wave per c
                b0 |= (uint64_t)(v.x < 0.0f) << c;
                b1 |= (uint64_t)(v.y < 0.0f) << c;
                b2 |= (uint64_t)(v.z < 0.0f) << c;
                b3 |= (uint64_t)(v.w < 0.0f) << c;
            }
        }
        uint64_t* dst = &tile[r][4 * g + 1];
        dst[0] = b0; dst[1] = b1; dst[2] = b2; dst[3] = b3;
    }
    if (tid < 20) tile[tid >> 1][(tid & 1) * 257] = 0;  // side pad columns

    __syncthreads();

    int l = tid & 63;       // lane -> pixel quad 4l..4l+3
    int wv = tid >> 6;      // wave -> row within stripe
    int h = h0 + wv;        // output row

    // X window: 3 padded rows, cols 4l..4l+5 (48B, 16B-aligned -> 3x ds_read_b128)
    uint64_t xw[3][6];
#pragma unroll
    for (int rr = 0; rr < 3; ++rr) {
        const uint64_t* rp = &tile[wv + rr][4 * l];
#pragma unroll
        for (int k = 0; k < 6; ++k) xw[rr][k] = rp[k];
    }

    bool isL = (l == 0), isR = (l == 63);
    bool isT = (h == 0), isB = (h == 255);
    float4* out4 = (float4*)out;
    size_t obase = (((size_t)n * CC) << 14) + (size_t)h * 64 + l;

#pragma unroll 2
    for (int o = 0; o < CC; ++o) {
        uint64_t q0 = sq[o][0], q1 = sq[o][1], q2 = sq[o][2];
        uint64_t q3 = sq[o][3], q4 = sq[o][4], q5 = sq[o][5];
        uint64_t q6 = sq[o][6], q7 = sq[o][7], q8 = sq[o][8];
        int hcorr = 0, cL = si[o][2], cR = si[o][3];
        if (isT) { hcorr += si[o][0]; cL -= si[o][4]; cR -= si[o][5]; }
        if (isB) { hcorr += si[o][1]; cL -= si[o][6]; cR -= si[o][7]; }
        float bo = sf[o][0], inv = sf[o][1], addc = sf[o][2];

        float4 res;
        float* resp = (float*)&res;
#pragma unroll
        for (int j = 0; j < 4; ++j) {
            int p = __popcll(xw[0][j] ^ q0) + __popcll(xw[0][j + 1] ^ q1) + __popcll(xw[0][j + 2] ^ q2)
                  + __popcll(xw[1][j] ^ q3) + __popcll(xw[1][j + 1] ^ q4) + __popcll(xw[1][j + 2] ^ q5)
                  + __popcll(xw[2][j] ^ q6) + __popcll(xw[2][j + 1] ^ q7) + __popcll(xw[2][j + 2] ^ q8);
            int corr = hcorr;
            if (j == 0 && isL) corr += cL;
            if (j == 3 && isR) corr += cR;
            float yf = (float)(576 - 2 * p - corr) + bo;
            yf = fmaxf(yf, 0.0f);
            resp[j] = fmaf(yf, inv, addc);
        }
        out4[obase + ((size_t)o << 14)] = res;  // wave store: 1KB contiguous
    }
}

extern "C" void kernel_launch(void* const* d_in, const int* in_sizes, int n_in,
                              void* d_out, int out_size, void* d_ws, size_t ws_size,
                              hipStream_t stream) {
    const float* x     = (const float*)d_in[0];
    const float* w     = (const float*)d_in[1];
    const float* bias  = (const float*)d_in[2];
    const float* gamma = (const float*)d_in[3];
    const float* beta  = (const float*)d_in[4];
    const float* rmean = (const float*)d_in[5];
    const float* rvar  = (const float*)d_in[6];
    float* out = (float*)d_out;

    uint64_t* pW = (uint64_t*)d_ws;  // 576 words

    pack_w_kernel<<<(CC * 9 + 3) / 4, 256, 0, stream>>>(w, pW);
    fused_kernel<<<NB * 32, 512, 0, stream>>>(x, pW, bias, gamma, beta, rmean, rvar, out);
}